// Round 1
// baseline (1092.191 us; speedup 1.0000x reference)
//
#include <hip/hip_runtime.h>
#include <hip/hip_bf16.h>

#define NN   512
#define DOBJ 256
#define DBOX 128
#define DIN  640
#define HID  256
#define DOUT 256

// workspace layout (float offsets)
#define OFF_A    0u        // A[i,k]  = W1a*obj_i + b1      [512,256]
#define OFF_B    131072u   // B[j,k]  = W1b*obj_j           [512,256]
#define OFF_CA   262144u   // Ca[i,k] = C1a*obj_i + cb1     [512,256]
#define OFF_CB   393216u   // Cb[j,k] = C1b*obj_j           [512,256]
#define OFF_WSV  524288u   // ws[k] = w2[k]*gamma[k]*rsqrt(var+eps)   [256]
#define OFF_S    524544u   // s[i] = sum_j conf[i,j]        [512]
#define OFF_CONF 525312u   // conf_raw then conf (in-place softmax) [512,512]
#define OFF_G    787456u   // G[i,k] = sum_j conf*g         [512,256]
// total 918528 floats = 3.67 MB

// ---------------------------------------------------------------- precompute
__global__ __launch_bounds__(256) void k_pre(
    const float* __restrict__ obj, const float* __restrict__ w1,
    const float* __restrict__ b1, const float* __restrict__ cw1,
    const float* __restrict__ cb1,
    float* __restrict__ A, float* __restrict__ B,
    float* __restrict__ Ca, float* __restrict__ Cb)
{
    const int i = blockIdx.x, k = threadIdx.x;
    __shared__ float o[DOBJ];
    o[k] = obj[(size_t)i * DOBJ + k];
    __syncthreads();
    const float* wr = w1 + (size_t)k * DIN;
    const float* cr = cw1 + (size_t)k * DIN;
    float a = 0.f, b = 0.f, ca = 0.f, cb = 0.f;
#pragma unroll 4
    for (int d = 0; d < DOBJ; ++d) {
        const float od = o[d];
        a  = fmaf(od, wr[d],        a);
        b  = fmaf(od, wr[DOBJ + d], b);
        ca = fmaf(od, cr[d],        ca);
        cb = fmaf(od, cr[DOBJ + d], cb);
    }
    A[(size_t)i * HID + k]  = a + b1[k];
    B[(size_t)i * HID + k]  = b;
    Ca[(size_t)i * HID + k] = ca + cb1[k];
    Cb[(size_t)i * HID + k] = cb;
}

__global__ void k_wsvec(const float* __restrict__ w2, const float* __restrict__ gamma,
                        const float* __restrict__ var, float* __restrict__ wsv)
{
    const int k = threadIdx.x;
    wsv[k] = w2[k] * gamma[k] * rsqrtf(var[k] + 1e-5f);
}

// ---------------------------------------------------------------- staging helpers
// bT[d][j]: 64 d x 64 j tile of bbox, d-major (transposed), pad 68
__device__ __forceinline__ void stage_bT(float (*bT)[68], const float* __restrict__ bbox,
                                         int i, int j0, int dc, int tid)
{
    const int lj = tid & 63, lq = tid >> 6;
    const float* src = bbox + ((size_t)i * NN + j0 + lj) * DBOX + dc * 64 + lq * 16;
#pragma unroll
    for (int u = 0; u < 4; ++u) {
        const float4 v = *(const float4*)(src + u * 4);
        const int d = lq * 16 + u * 4;
        bT[d + 0][lj] = v.x; bT[d + 1][lj] = v.y;
        bT[d + 2][lj] = v.z; bT[d + 3][lj] = v.w;
    }
}

// wT[d][k]: 64 d x 128 k tile of weight cols [512..640), d-major, pad 132
__device__ __forceinline__ void stage_wT(float (*wT)[132], const float* __restrict__ w,
                                         int ks, int dc, int tid)
{
    const int kk = tid & 127, h = tid >> 7;
    const float* src = w + (size_t)(ks * 128 + kk) * DIN + 2 * DOBJ + dc * 64 + h * 32;
#pragma unroll
    for (int u = 0; u < 8; ++u) {
        const float4 v = *(const float4*)(src + u * 4);
        const int d = h * 32 + u * 4;
        wT[d + 0][kk] = v.x; wT[d + 1][kk] = v.y;
        wT[d + 2][kk] = v.z; wT[d + 3][kk] = v.w;
    }
}

// 64-deep K-slab: acc[4 j][8 k] += bbox-tile * weight-tile
__device__ __forceinline__ void gemm64(const float (*bT)[68], const float (*wT)[132],
                                       int tj, int tk, float acc[4][8])
{
    for (int d = 0; d < 64; ++d) {
        const float4 a4 = *(const float4*)&bT[d][tj * 4];
        const float4 b0 = *(const float4*)&wT[d][tk * 8];
        const float4 b1 = *(const float4*)&wT[d][tk * 8 + 4];
        const float av[4] = {a4.x, a4.y, a4.z, a4.w};
        const float bv[8] = {b0.x, b0.y, b0.z, b0.w, b1.x, b1.y, b1.z, b1.w};
#pragma unroll
        for (int jj = 0; jj < 4; ++jj)
#pragma unroll
            for (int kk = 0; kk < 8; ++kk)
                acc[jj][kk] = fmaf(av[jj], bv[kk], acc[jj][kk]);
    }
}

// ---------------------------------------------------------------- conf_raw
// block = (i, 64-j tile); conf_raw[i,j] = sum_k ws[k]*leaky(A[i,k]+B[j,k]+bbox@W1c^T)
__global__ __launch_bounds__(256) void k_conf(
    const float* __restrict__ bbox, const float* __restrict__ w1,
    const float* __restrict__ A, const float* __restrict__ B,
    const float* __restrict__ wsv, float* __restrict__ conf_raw)
{
    const int i = blockIdx.y;
    const int j0 = blockIdx.x * 64;
    const int tid = threadIdx.x;
    const int tj = tid & 15, tk = tid >> 4;

    __shared__ float bT[64][68];
    __shared__ float wT[64][132];
    __shared__ float A_s[HID];
    __shared__ float ws_s[HID];
    __shared__ float red[64][17];

    A_s[tid]  = A[(size_t)i * HID + tid];
    ws_s[tid] = wsv[tid];

    float acc0[4][8], acc1[4][8];
#pragma unroll
    for (int a = 0; a < 4; ++a)
#pragma unroll
        for (int b = 0; b < 8; ++b) { acc0[a][b] = 0.f; acc1[a][b] = 0.f; }

#pragma unroll
    for (int dc = 0; dc < 2; ++dc) {
        __syncthreads();
        stage_bT(bT, bbox, i, j0, dc, tid);
        stage_wT(wT, w1, 0, dc, tid);
        __syncthreads();
        gemm64(bT, wT, tj, tk, acc0);
        __syncthreads();
        stage_wT(wT, w1, 1, dc, tid);
        __syncthreads();
        gemm64(bT, wT, tj, tk, acc1);
    }

    float pj[4] = {0.f, 0.f, 0.f, 0.f};
#pragma unroll
    for (int jj = 0; jj < 4; ++jj) {
        const int j = j0 + tj * 4 + jj;
        const float* B0 = B + (size_t)j * HID + tk * 8;
#pragma unroll
        for (int kk = 0; kk < 8; ++kk) {
            const int k0 = tk * 8 + kk, k1 = 128 + tk * 8 + kk;
            float t0 = acc0[jj][kk] + A_s[k0] + B0[kk];
            float t1 = acc1[jj][kk] + A_s[k1] + B0[128 + kk];
            t0 = t0 > 0.f ? t0 : 0.01f * t0;
            t1 = t1 > 0.f ? t1 : 0.01f * t1;
            pj[jj] = fmaf(t0, ws_s[k0], pj[jj]);
            pj[jj] = fmaf(t1, ws_s[k1], pj[jj]);
        }
    }

#pragma unroll
    for (int jj = 0; jj < 4; ++jj) red[tj * 4 + jj][tk] = pj[jj];
    __syncthreads();
    if (tid < 64) {
        float s = 0.f;
#pragma unroll
        for (int t2 = 0; t2 < 16; ++t2) s += red[tid][t2];
        conf_raw[(size_t)i * NN + j0 + tid] = s;
    }
}

// ---------------------------------------------------------------- row softmax+mask+renorm
__global__ __launch_bounds__(256) void k_softmax(
    const float* __restrict__ conf_raw, const float* __restrict__ mask,
    float* __restrict__ conf, float* __restrict__ s_out)
{
    const int i = blockIdx.x, tid = threadIdx.x;
    const int lane = tid & 63, w = tid >> 6;
    __shared__ float wred[3][4];

    const float r0 = conf_raw[(size_t)i * NN + tid];
    const float r1 = conf_raw[(size_t)i * NN + 256 + tid];
    const float mk0 = mask[(size_t)i * NN + tid];
    const float mk1 = mask[(size_t)i * NN + 256 + tid];

    float m = fmaxf(r0, r1);
#pragma unroll
    for (int off = 32; off; off >>= 1) m = fmaxf(m, __shfl_down(m, off));
    if (lane == 0) wred[0][w] = m;
    __syncthreads();
    const float M = fmaxf(fmaxf(wred[0][0], wred[0][1]), fmaxf(wred[0][2], wred[0][3]));

    const float e0 = __expf(r0 - M), e1 = __expf(r1 - M);
    float sa = e0 + e1;
    float sk = e0 * mk0 + e1 * mk1;
#pragma unroll
    for (int off = 32; off; off >>= 1) {
        sa += __shfl_down(sa, off);
        sk += __shfl_down(sk, off);
    }
    if (lane == 0) { wred[1][w] = sa; wred[2][w] = sk; }
    __syncthreads();
    const float SA = wred[1][0] + wred[1][1] + wred[1][2] + wred[1][3];
    const float SK = wred[2][0] + wred[2][1] + wred[2][2] + wred[2][3];
    const float dinv = 1.f / (SK + 1e-8f * SA);

    conf[(size_t)i * NN + tid]       = e0 * mk0 * dinv;
    conf[(size_t)i * NN + 256 + tid] = e1 * mk1 * dinv;
    if (tid == 0) s_out[i] = SK * dinv;
}

// ---------------------------------------------------------------- weighted g accumulate
// block = (i, 64-j tile); G[i,k] += sum_j conf[i,j]*relu(Ca[i,k]+Cb[j,k]+bbox@C1c^T)
__global__ __launch_bounds__(256) void k_gacc(
    const float* __restrict__ bbox, const float* __restrict__ cw1,
    const float* __restrict__ Ca, const float* __restrict__ Cb,
    const float* __restrict__ conf, float* __restrict__ G)
{
    const int i = blockIdx.y;
    const int j0 = blockIdx.x * 64;
    const int tid = threadIdx.x;
    const int tj = tid & 15, tk = tid >> 4;

    __shared__ float bT[64][68];
    __shared__ float wT[64][132];
    __shared__ float Ca_s[HID];
    __shared__ float conf_s[64];
    __shared__ float red[128][17];

    Ca_s[tid] = Ca[(size_t)i * HID + tid];
    if (tid < 64) conf_s[tid] = conf[(size_t)i * NN + j0 + tid];

    float acc0[4][8], acc1[4][8];
#pragma unroll
    for (int a = 0; a < 4; ++a)
#pragma unroll
        for (int b = 0; b < 8; ++b) { acc0[a][b] = 0.f; acc1[a][b] = 0.f; }

#pragma unroll
    for (int dc = 0; dc < 2; ++dc) {
        __syncthreads();
        stage_bT(bT, bbox, i, j0, dc, tid);
        stage_wT(wT, cw1, 0, dc, tid);
        __syncthreads();
        gemm64(bT, wT, tj, tk, acc0);
        __syncthreads();
        stage_wT(wT, cw1, 1, dc, tid);
        __syncthreads();
        gemm64(bT, wT, tj, tk, acc1);
    }

    float ga0[8] = {0.f,0.f,0.f,0.f,0.f,0.f,0.f,0.f};
    float ga1[8] = {0.f,0.f,0.f,0.f,0.f,0.f,0.f,0.f};
#pragma unroll
    for (int jj = 0; jj < 4; ++jj) {
        const int jL = tj * 4 + jj;
        const int j = j0 + jL;
        const float cf = conf_s[jL];
        const float* Cb0 = Cb + (size_t)j * HID + tk * 8;
#pragma unroll
        for (int kk = 0; kk < 8; ++kk) {
            const float t0 = acc0[jj][kk] + Ca_s[tk * 8 + kk] + Cb0[kk];
            const float t1 = acc1[jj][kk] + Ca_s[128 + tk * 8 + kk] + Cb0[128 + kk];
            ga0[kk] = fmaf(cf, fmaxf(t0, 0.f), ga0[kk]);
            ga1[kk] = fmaf(cf, fmaxf(t1, 0.f), ga1[kk]);
        }
    }

    __syncthreads();
#pragma unroll
    for (int kk = 0; kk < 8; ++kk) red[tk * 8 + kk][tj] = ga0[kk];
    __syncthreads();
    if (tid < 128) {
        float s = 0.f;
#pragma unroll
        for (int t2 = 0; t2 < 16; ++t2) s += red[tid][t2];
        atomicAdd(&G[(size_t)i * DOUT + tid], s);
    }
    __syncthreads();
#pragma unroll
    for (int kk = 0; kk < 8; ++kk) red[tk * 8 + kk][tj] = ga1[kk];
    __syncthreads();
    if (tid < 128) {
        float s = 0.f;
#pragma unroll
        for (int t2 = 0; t2 < 16; ++t2) s += red[tid][t2];
        atomicAdd(&G[(size_t)i * DOUT + 128 + tid], s);
    }
}

// ---------------------------------------------------------------- final small GEMM
__global__ __launch_bounds__(256) void k_out(
    const float* __restrict__ G, const float* __restrict__ cw2,
    const float* __restrict__ cb2, const float* __restrict__ s_in,
    float* __restrict__ out)
{
    const int i = blockIdx.x, o = threadIdx.x;
    __shared__ float Gs[DOUT];
    Gs[o] = G[(size_t)i * DOUT + o];
    __syncthreads();
    const float* wr = cw2 + (size_t)o * HID;
    float acc = 0.f;
#pragma unroll 4
    for (int k = 0; k < HID; ++k) acc = fmaf(Gs[k], wr[k], acc);
    out[(size_t)i * DOUT + o] = acc + s_in[i] * cb2[o];
}

// ---------------------------------------------------------------- launch
extern "C" void kernel_launch(void* const* d_in, const int* in_sizes, int n_in,
                              void* d_out, int out_size, void* d_ws, size_t ws_size,
                              hipStream_t stream)
{
    const float* obj  = (const float*)d_in[0];
    const float* bbox = (const float*)d_in[1];
    const float* mask = (const float*)d_in[2];
    const float* w1   = (const float*)d_in[3];
    const float* b1   = (const float*)d_in[4];
    const float* bn_g = (const float*)d_in[5];
    // d_in[6] bn_beta, d_in[7] bn_mean, d_in[10] b2: pair-independent constants in
    // the pre-softmax logits -> cancel in softmax; unused.
    const float* bn_v = (const float*)d_in[8];
    const float* w2   = (const float*)d_in[9];
    const float* cw1  = (const float*)d_in[11];
    const float* cb1  = (const float*)d_in[12];
    const float* cw2  = (const float*)d_in[13];
    const float* cb2  = (const float*)d_in[14];

    float* ws   = (float*)d_ws;
    float* A    = ws + OFF_A;
    float* B    = ws + OFF_B;
    float* Ca   = ws + OFF_CA;
    float* Cb   = ws + OFF_CB;
    float* wsv  = ws + OFF_WSV;
    float* sbuf = ws + OFF_S;
    float* conf = ws + OFF_CONF;
    float* G    = ws + OFF_G;
    float* out  = (float*)d_out;

    k_pre<<<NN, 256, 0, stream>>>(obj, w1, b1, cw1, cb1, A, B, Ca, Cb);
    k_wsvec<<<1, 256, 0, stream>>>(w2, bn_g, bn_v, wsv);
    k_conf<<<dim3(8, NN), 256, 0, stream>>>(bbox, w1, A, B, wsv, conf);
    k_softmax<<<NN, 256, 0, stream>>>(conf, mask, conf, sbuf);
    hipMemsetAsync(G, 0, (size_t)NN * DOUT * sizeof(float), stream);
    k_gacc<<<dim3(8, NN), 256, 0, stream>>>(bbox, cw1, Ca, Cb, conf, G);
    k_out<<<NN, 256, 0, stream>>>(G, cw2, cb2, sbuf, out);
}

// Round 2
// 727.037 us; speedup vs baseline: 1.5022x; 1.5022x over previous
//
#include <hip/hip_runtime.h>
#include <hip/hip_bf16.h>

#define NN   512
#define DOBJ 256
#define DBOX 128
#define DIN  640
#define HID  256
#define DOUT 256

typedef __attribute__((ext_vector_type(8))) short  short8;  // bf16x8 MFMA frag
typedef __attribute__((ext_vector_type(4))) float  f32x4;

// workspace layout (float offsets)
#define OFF_A    0u        // A[i,k]  = W1a*obj_i + b1      [512,256]
#define OFF_B    131072u   // B[j,k]  = W1b*obj_j           [512,256]
#define OFF_CA   262144u   // Ca[i,k] = C1a*obj_i + cb1    [512,256]
#define OFF_CB   393216u   // Cb[j,k] = C1b*obj_j          [512,256]
#define OFF_WSV  524288u   // ws[k] = w2*gamma*rsqrt(var+eps) [256]
#define OFF_S    524544u   // s[i] = sum_j conf             [512]
#define OFF_CONF 525312u   // conf_raw then conf            [512,512]
#define OFF_G    787456u   // G[i,k]                        [512,256]
#define OFF_WSWZ 918528u   // 2 mats x 32768 ushort (128 KB), swizzled bf16 weights

// ---------------------------------------------------------------- helpers
__device__ __forceinline__ ushort bf16u(float x) {
    __hip_bfloat16 h = __float2bfloat16(x);
    union { __hip_bfloat16 b; ushort u; } c; c.b = h;
    return c.u;
}

__device__ __forceinline__ short8 cvt8(float4 a, float4 b) {
    short8 o;
    o[0] = (short)bf16u(a.x); o[1] = (short)bf16u(a.y);
    o[2] = (short)bf16u(a.z); o[3] = (short)bf16u(a.w);
    o[4] = (short)bf16u(b.x); o[5] = (short)bf16u(b.y);
    o[6] = (short)bf16u(b.z); o[7] = (short)bf16u(b.w);
    return o;
}

// ---------------------------------------------------------------- precompute (unchanged)
__global__ __launch_bounds__(256) void k_pre(
    const float* __restrict__ obj, const float* __restrict__ w1,
    const float* __restrict__ b1, const float* __restrict__ cw1,
    const float* __restrict__ cb1,
    float* __restrict__ A, float* __restrict__ B,
    float* __restrict__ Ca, float* __restrict__ Cb)
{
    const int i = blockIdx.x, k = threadIdx.x;
    __shared__ float o[DOBJ];
    o[k] = obj[(size_t)i * DOBJ + k];
    __syncthreads();
    const float* wr = w1 + (size_t)k * DIN;
    const float* cr = cw1 + (size_t)k * DIN;
    float a = 0.f, b = 0.f, ca = 0.f, cb = 0.f;
#pragma unroll 4
    for (int d = 0; d < DOBJ; ++d) {
        const float od = o[d];
        a  = fmaf(od, wr[d],        a);
        b  = fmaf(od, wr[DOBJ + d], b);
        ca = fmaf(od, cr[d],        ca);
        cb = fmaf(od, cr[DOBJ + d], cb);
    }
    A[(size_t)i * HID + k]  = a + b1[k];
    B[(size_t)i * HID + k]  = b;
    Ca[(size_t)i * HID + k] = ca + cb1[k];
    Cb[(size_t)i * HID + k] = cb;
}

__global__ void k_wsvec(const float* __restrict__ w2, const float* __restrict__ gamma,
                        const float* __restrict__ var, float* __restrict__ wsv)
{
    const int k = threadIdx.x;
    wsv[k] = w2[k] * gamma[k] * rsqrtf(var[k] + 1e-5f);
}

// Convert bbox-weight blocks (cols 512..639) of w1 / cw1 to bf16 in the
// LDS-image, chunk-XOR-swizzled layout: ushort idx = k*128 + ((d>>3 ^ (k&7))<<3) + (d&7)
__global__ __launch_bounds__(128) void k_wprep(
    const float* __restrict__ w1, const float* __restrict__ cw1,
    ushort* __restrict__ wswz)
{
    const int k = blockIdx.x, mat = blockIdx.y, d = threadIdx.x;
    const float* src = mat ? cw1 : w1;
    const float v = src[(size_t)k * DIN + 2 * DOBJ + d];
    const int c = d >> 3;
    const int idx = k * 128 + (((c ^ (k & 7)) << 3)) + (d & 7);
    wswz[(size_t)mat * 32768 + idx] = bf16u(v);
}

// ---------------------------------------------------------------- MFMA pair-GEMM
// grid (8 jt, 512 i), 256 thr (4 waves). wave w owns k-cols [w*64, w*64+64),
// all 64 j rows. A-frags: global fp32 bbox + cvt. B-frags: swizzled LDS bf16.
// Same k-bijection (kappa = 8*lanegroup + elem) for A and B frags => layout-safe.
template<int GACC>
__global__ __launch_bounds__(256, 2) void k_pair(
    const float* __restrict__ bbox, const ushort* __restrict__ wswz,
    const float* __restrict__ Arow,   // conf: A[i,k]   ; gacc: Ca[i,k]
    const float* __restrict__ Bcol,   // conf: B[j,k]   ; gacc: Cb[j,k]
    const float* __restrict__ aux,    // conf: ws[256]  ; gacc: conf[512,512]
    float* __restrict__ outp)         // conf: conf_raw ; gacc: G (pre-zeroed)
{
    const int i  = blockIdx.y;
    const int j0 = blockIdx.x * 64;
    const int tid = threadIdx.x;
    const int w = tid >> 6, lane = tid & 63;
    const int lr = lane & 15, lg = lane >> 4;

    __shared__ ushort wlds[32768];       // 64 KB swizzled weights
    __shared__ float  red[4][64];
    __shared__ float  conf_s[64];

    // stage weights: 16 x 16B per thread, contiguous image copy
    {
        const uint4* g = (const uint4*)wswz;
        uint4* l = (uint4*)wlds;
#pragma unroll
        for (int n = 0; n < 16; ++n) l[n * 256 + tid] = g[n * 256 + tid];
    }
    if (GACC && tid < 64) conf_s[tid] = aux[(size_t)i * NN + j0 + tid];
    __syncthreads();

    // per-lane epilogue constants for k = w*64 + t*16 + lr
    float as_t[4], ws_t[4];
#pragma unroll
    for (int t = 0; t < 4; ++t) {
        const int kk = w * 64 + t * 16 + lr;
        as_t[t] = Arow[(size_t)i * HID + kk];
        ws_t[t] = GACC ? 0.f : aux[kk];
    }

    f32x4 acc[4][4];  // [ms][t]
#pragma unroll
    for (int a = 0; a < 4; ++a)
#pragma unroll
        for (int b = 0; b < 4; ++b) acc[a][b] = (f32x4){0.f, 0.f, 0.f, 0.f};

#pragma unroll
    for (int ks = 0; ks < 4; ++ks) {
        short8 bf[4];
#pragma unroll
        for (int t = 0; t < 4; ++t) {
            const int kk = w * 64 + t * 16 + lr;
            const int c  = (ks * 4 + lg) ^ (lr & 7);
            bf[t] = *(const short8*)&wlds[kk * 128 + (c << 3)];
        }
#pragma unroll
        for (int ms = 0; ms < 4; ++ms) {
            const float* ap = bbox +
                (((size_t)i * NN + j0 + ms * 16 + lr) * DBOX + ks * 32 + lg * 8);
            const float4 a0 = *(const float4*)ap;
            const float4 a1 = *(const float4*)(ap + 4);
            const short8 af = cvt8(a0, a1);
#pragma unroll
            for (int t = 0; t < 4; ++t)
                acc[ms][t] = __builtin_amdgcn_mfma_f32_16x16x32_bf16(
                    af, bf[t], acc[ms][t], 0, 0, 0);
        }
    }

    if (!GACC) {
        // conf_raw[i,j] = sum_k ws[k] * leaky(P + A[i,k] + B[j,k])
        float pj[4][4];  // [ms][r]
#pragma unroll
        for (int a = 0; a < 4; ++a)
#pragma unroll
            for (int b = 0; b < 4; ++b) pj[a][b] = 0.f;
#pragma unroll
        for (int ms = 0; ms < 4; ++ms)
#pragma unroll
            for (int r = 0; r < 4; ++r) {
                const int j = j0 + ms * 16 + lg * 4 + r;
                const float* Bj = Bcol + (size_t)j * HID + w * 64 + lr;
#pragma unroll
                for (int t = 0; t < 4; ++t) {
                    float h = acc[ms][t][r] + as_t[t] + Bj[t * 16];
                    h = fmaxf(h, 0.01f * h);           // LeakyReLU
                    pj[ms][r] = fmaf(h, ws_t[t], pj[ms][r]);
                }
            }
        // reduce over the 16 k-lanes (lr) of each lane-group
#pragma unroll
        for (int ms = 0; ms < 4; ++ms)
#pragma unroll
            for (int r = 0; r < 4; ++r) {
                float v = pj[ms][r];
                v += __shfl_xor(v, 1);  v += __shfl_xor(v, 2);
                v += __shfl_xor(v, 4);  v += __shfl_xor(v, 8);
                if (lr == 0) red[w][ms * 16 + lg * 4 + r] = v;
            }
        __syncthreads();
        if (tid < 64)
            outp[(size_t)i * NN + j0 + tid] =
                red[0][tid] + red[1][tid] + red[2][tid] + red[3][tid];
    } else {
        // G[i,k] += sum_j conf[i,j] * relu(P + Ca[i,k] + Cb[j,k])
        float cf[4][4];
#pragma unroll
        for (int ms = 0; ms < 4; ++ms)
#pragma unroll
            for (int r = 0; r < 4; ++r) cf[ms][r] = conf_s[ms * 16 + lg * 4 + r];
        float gk[4] = {0.f, 0.f, 0.f, 0.f};
#pragma unroll
        for (int ms = 0; ms < 4; ++ms)
#pragma unroll
            for (int r = 0; r < 4; ++r) {
                const int j = j0 + ms * 16 + lg * 4 + r;
                const float* Bj = Bcol + (size_t)j * HID + w * 64 + lr;
#pragma unroll
                for (int t = 0; t < 4; ++t) {
                    float h = acc[ms][t][r] + as_t[t] + Bj[t * 16];
                    h = fmaxf(h, 0.f);
                    gk[t] = fmaf(cf[ms][r], h, gk[t]);
                }
            }
#pragma unroll
        for (int t = 0; t < 4; ++t) {
            float v = gk[t];
            v += __shfl_xor(v, 16);
            v += __shfl_xor(v, 32);
            if (lg == 0)
                atomicAdd(&outp[(size_t)i * DOUT + w * 64 + t * 16 + lr], v);
        }
    }
}

// ---------------------------------------------------------------- row softmax (unchanged)
__global__ __launch_bounds__(256) void k_softmax(
    const float* __restrict__ conf_raw, const float* __restrict__ mask,
    float* __restrict__ conf, float* __restrict__ s_out)
{
    const int i = blockIdx.x, tid = threadIdx.x;
    const int lane = tid & 63, w = tid >> 6;
    __shared__ float wred[3][4];

    const float r0 = conf_raw[(size_t)i * NN + tid];
    const float r1 = conf_raw[(size_t)i * NN + 256 + tid];
    const float mk0 = mask[(size_t)i * NN + tid];
    const float mk1 = mask[(size_t)i * NN + 256 + tid];

    float m = fmaxf(r0, r1);
#pragma unroll
    for (int off = 32; off; off >>= 1) m = fmaxf(m, __shfl_down(m, off));
    if (lane == 0) wred[0][w] = m;
    __syncthreads();
    const float M = fmaxf(fmaxf(wred[0][0], wred[0][1]), fmaxf(wred[0][2], wred[0][3]));

    const float e0 = __expf(r0 - M), e1 = __expf(r1 - M);
    float sa = e0 + e1;
    float sk = e0 * mk0 + e1 * mk1;
#pragma unroll
    for (int off = 32; off; off >>= 1) {
        sa += __shfl_down(sa, off);
        sk += __shfl_down(sk, off);
    }
    if (lane == 0) { wred[1][w] = sa; wred[2][w] = sk; }
    __syncthreads();
    const float SA = wred[1][0] + wred[1][1] + wred[1][2] + wred[1][3];
    const float SK = wred[2][0] + wred[2][1] + wred[2][2] + wred[2][3];
    const float dinv = 1.f / (SK + 1e-8f * SA);

    conf[(size_t)i * NN + tid]       = e0 * mk0 * dinv;
    conf[(size_t)i * NN + 256 + tid] = e1 * mk1 * dinv;
    if (tid == 0) s_out[i] = SK * dinv;
}

// ---------------------------------------------------------------- final small GEMM (unchanged)
__global__ __launch_bounds__(256) void k_out(
    const float* __restrict__ G, const float* __restrict__ cw2,
    const float* __restrict__ cb2, const float* __restrict__ s_in,
    float* __restrict__ out)
{
    const int i = blockIdx.x, o = threadIdx.x;
    __shared__ float Gs[DOUT];
    Gs[o] = G[(size_t)i * DOUT + o];
    __syncthreads();
    const float* wr = cw2 + (size_t)o * HID;
    float acc = 0.f;
#pragma unroll 4
    for (int k = 0; k < HID; ++k) acc = fmaf(Gs[k], wr[k], acc);
    out[(size_t)i * DOUT + o] = acc + s_in[i] * cb2[o];
}

// ---------------------------------------------------------------- launch
extern "C" void kernel_launch(void* const* d_in, const int* in_sizes, int n_in,
                              void* d_out, int out_size, void* d_ws, size_t ws_size,
                              hipStream_t stream)
{
    const float* obj  = (const float*)d_in[0];
    const float* bbox = (const float*)d_in[1];
    const float* mask = (const float*)d_in[2];
    const float* w1   = (const float*)d_in[3];
    const float* b1   = (const float*)d_in[4];
    const float* bn_g = (const float*)d_in[5];
    const float* bn_v = (const float*)d_in[8];
    const float* w2   = (const float*)d_in[9];
    const float* cw1  = (const float*)d_in[11];
    const float* cb1  = (const float*)d_in[12];
    const float* cw2  = (const float*)d_in[13];
    const float* cb2  = (const float*)d_in[14];

    float* ws   = (float*)d_ws;
    float* A    = ws + OFF_A;
    float* B    = ws + OFF_B;
    float* Ca   = ws + OFF_CA;
    float* Cb   = ws + OFF_CB;
    float* wsv  = ws + OFF_WSV;
    float* sbuf = ws + OFF_S;
    float* conf = ws + OFF_CONF;
    float* G    = ws + OFF_G;
    ushort* wswz = (ushort*)(ws + OFF_WSWZ);
    float* out  = (float*)d_out;

    k_pre<<<NN, 256, 0, stream>>>(obj, w1, b1, cw1, cb1, A, B, Ca, Cb);
    k_wsvec<<<1, 256, 0, stream>>>(w2, bn_g, bn_v, wsv);
    k_wprep<<<dim3(256, 2), 128, 0, stream>>>(w1, cw1, wswz);
    k_pair<0><<<dim3(8, NN), 256, 0, stream>>>(bbox, wswz, A, B, wsv, conf);
    k_softmax<<<NN, 256, 0, stream>>>(conf, mask, conf, sbuf);
    hipMemsetAsync(G, 0, (size_t)NN * DOUT * sizeof(float), stream);
    k_pair<1><<<dim3(8, NN), 256, 0, stream>>>(bbox, wswz + 32768, Ca, Cb, conf, G);
    k_out<<<NN, 256, 0, stream>>>(G, cw2, cb2, sbuf, out);
}

// Round 3
// 451.437 us; speedup vs baseline: 2.4194x; 1.6105x over previous
//
#include <hip/hip_runtime.h>
#include <hip/hip_bf16.h>

#define NN   512
#define DOBJ 256
#define DBOX 128
#define DIN  640
#define HID  256
#define DOUT 256

typedef __attribute__((ext_vector_type(8))) short  short8;  // bf16x8 MFMA frag
typedef __attribute__((ext_vector_type(4))) float  f32x4;

// workspace layout (float offsets)
#define OFF_A    0u        // A[i,k]  = W1a*obj_i + b1      [512,256]
#define OFF_B    131072u   // B[j,k]  = W1b*obj_j           [512,256]
#define OFF_CA   262144u   // Ca[i,k] = C1a*obj_i + cb1    [512,256]
#define OFF_CB   393216u   // Cb[j,k] = C1b*obj_j          [512,256]
#define OFF_WSV  524288u   // ws[k] = w2*gamma*rsqrt(var+eps) [256]
#define OFF_S    524544u   // s[i] = sum_j conf             [512]
#define OFF_CONF 525312u   // conf_raw then conf            [512,512]
#define OFF_G    787456u   // G[i,k]                        [512,256]
#define OFF_WSWZ 918528u   // 2 mats x 32768 ushort (128 KB), swizzled bf16 weights

// ---------------------------------------------------------------- helpers
__device__ __forceinline__ ushort bf16u(float x) {
    __hip_bfloat16 h = __float2bfloat16(x);
    union { __hip_bfloat16 b; ushort u; } c; c.b = h;
    return c.u;
}

__device__ __forceinline__ short8 cvt8(float4 a, float4 b) {
    short8 o;
    o[0] = (short)bf16u(a.x); o[1] = (short)bf16u(a.y);
    o[2] = (short)bf16u(a.z); o[3] = (short)bf16u(a.w);
    o[4] = (short)bf16u(b.x); o[5] = (short)bf16u(b.y);
    o[6] = (short)bf16u(b.z); o[7] = (short)bf16u(b.w);
    return o;
}

// ---------------------------------------------------------------- precompute via MFMA
// A|B|Ca|Cb = obj[512,256] @ {w1a,w1b,cw1a,cw1b}^T, one 256-col panel per blockIdx.x.
// Same-kappa fragment discipline as k_pair (k = ks*32 + lg*8 + e for A and B).
__global__ __launch_bounds__(256, 2) void k_pre_mfma(
    const float* __restrict__ obj, const float* __restrict__ w1,
    const float* __restrict__ cw1, const float* __restrict__ b1,
    const float* __restrict__ cb1,
    float* __restrict__ A, float* __restrict__ B,
    float* __restrict__ Ca, float* __restrict__ Cb)
{
    const int bx = blockIdx.x;            // 0:A 1:B 2:Ca 3:Cb
    const int i0 = blockIdx.y * 64;
    const int tid = threadIdx.x;
    const int w = tid >> 6, lane = tid & 63;
    const int lr = lane & 15, lg = lane >> 4;

    const float* src = (bx & 2) ? cw1 : w1;
    const int dof = (bx & 1) * DOBJ;      // a-part cols 0..255, b-part 256..511

    f32x4 acc[4][4];
#pragma unroll
    for (int a = 0; a < 4; ++a)
#pragma unroll
        for (int b = 0; b < 4; ++b) acc[a][b] = (f32x4){0.f, 0.f, 0.f, 0.f};

#pragma unroll
    for (int ks = 0; ks < 8; ++ks) {
        short8 af[4], bf[4];
#pragma unroll
        for (int ms = 0; ms < 4; ++ms) {
            const float* ap = obj + (size_t)(i0 + ms * 16 + lr) * DOBJ + ks * 32 + lg * 8;
            af[ms] = cvt8(*(const float4*)ap, *(const float4*)(ap + 4));
        }
#pragma unroll
        for (int t = 0; t < 4; ++t) {
            const int kc = w * 64 + t * 16 + lr;
            const float* bp = src + (size_t)kc * DIN + dof + ks * 32 + lg * 8;
            bf[t] = cvt8(*(const float4*)bp, *(const float4*)(bp + 4));
        }
#pragma unroll
        for (int ms = 0; ms < 4; ++ms)
#pragma unroll
            for (int t = 0; t < 4; ++t)
                acc[ms][t] = __builtin_amdgcn_mfma_f32_16x16x32_bf16(
                    af[ms], bf[t], acc[ms][t], 0, 0, 0);
    }

    float* dst = (bx == 0) ? A : (bx == 1) ? B : (bx == 2) ? Ca : Cb;
    const float* bias = (bx == 0) ? b1 : (bx == 2) ? cb1 : nullptr;
    float bb[4];
#pragma unroll
    for (int t = 0; t < 4; ++t)
        bb[t] = bias ? bias[w * 64 + t * 16 + lr] : 0.f;

#pragma unroll
    for (int ms = 0; ms < 4; ++ms)
#pragma unroll
        for (int t = 0; t < 4; ++t)
#pragma unroll
            for (int r = 0; r < 4; ++r) {
                const int i = i0 + ms * 16 + lg * 4 + r;
                const int kc = w * 64 + t * 16 + lr;
                dst[(size_t)i * HID + kc] = acc[ms][t][r] + bb[t];
            }
}

__global__ void k_wsvec(const float* __restrict__ w2, const float* __restrict__ gamma,
                        const float* __restrict__ var, float* __restrict__ wsv)
{
    const int k = threadIdx.x;
    wsv[k] = w2[k] * gamma[k] * rsqrtf(var[k] + 1e-5f);
}

// Convert bbox-weight blocks (cols 512..639) of w1 / cw1 to bf16 in the
// LDS-image, chunk-XOR-swizzled layout: ushort idx = k*128 + ((d>>3 ^ (k&7))<<3) + (d&7)
__global__ __launch_bounds__(128) void k_wprep(
    const float* __restrict__ w1, const float* __restrict__ cw1,
    ushort* __restrict__ wswz)
{
    const int k = blockIdx.x, mat = blockIdx.y, d = threadIdx.x;
    const float* src = mat ? cw1 : w1;
    const float v = src[(size_t)k * DIN + 2 * DOBJ + d];
    const int c = d >> 3;
    const int idx = k * 128 + (((c ^ (k & 7)) << 3)) + (d & 7);
    wswz[(size_t)mat * 32768 + idx] = bf16u(v);
}

// ---------------------------------------------------------------- MFMA pair-GEMM
// grid (8 jt, 512 i), 256 thr (4 waves). wave w owns k-cols [w*64, w*64+64),
// all 64 j rows. A-frags: global fp32 bbox + cvt. B-frags: swizzled LDS bf16.
template<int GACC>
__global__ __launch_bounds__(256, 2) void k_pair(
    const float* __restrict__ bbox, const ushort* __restrict__ wswz,
    const float* __restrict__ Arow,   // conf: A[i,k]   ; gacc: Ca[i,k]
    const float* __restrict__ Bcol,   // conf: B[j,k]   ; gacc: Cb[j,k]
    const float* __restrict__ aux,    // conf: ws[256]  ; gacc: conf[512,512]
    float* __restrict__ outp)         // conf: conf_raw ; gacc: G (pre-zeroed)
{
    const int i  = blockIdx.y;
    const int j0 = blockIdx.x * 64;
    const int tid = threadIdx.x;
    const int w = tid >> 6, lane = tid & 63;
    const int lr = lane & 15, lg = lane >> 4;

    __shared__ ushort wlds[32768];       // 64 KB swizzled weights
    __shared__ float  red[4][64];
    __shared__ float  conf_s[64];

    {
        const uint4* g = (const uint4*)wswz;
        uint4* l = (uint4*)wlds;
#pragma unroll
        for (int n = 0; n < 16; ++n) l[n * 256 + tid] = g[n * 256 + tid];
    }
    if (GACC && tid < 64) conf_s[tid] = aux[(size_t)i * NN + j0 + tid];
    __syncthreads();

    float as_t[4], ws_t[4];
#pragma unroll
    for (int t = 0; t < 4; ++t) {
        const int kk = w * 64 + t * 16 + lr;
        as_t[t] = Arow[(size_t)i * HID + kk];
        ws_t[t] = GACC ? 0.f : aux[kk];
    }

    f32x4 acc[4][4];  // [ms][t]
#pragma unroll
    for (int a = 0; a < 4; ++a)
#pragma unroll
        for (int b = 0; b < 4; ++b) acc[a][b] = (f32x4){0.f, 0.f, 0.f, 0.f};

#pragma unroll
    for (int ks = 0; ks < 4; ++ks) {
        short8 bf[4];
#pragma unroll
        for (int t = 0; t < 4; ++t) {
            const int kk = w * 64 + t * 16 + lr;
            const int c  = (ks * 4 + lg) ^ (lr & 7);
            bf[t] = *(const short8*)&wlds[kk * 128 + (c << 3)];
        }
#pragma unroll
        for (int ms = 0; ms < 4; ++ms) {
            const float* ap = bbox +
                (((size_t)i * NN + j0 + ms * 16 + lr) * DBOX + ks * 32 + lg * 8);
            const float4 a0 = *(const float4*)ap;
            const float4 a1 = *(const float4*)(ap + 4);
            const short8 af = cvt8(a0, a1);
#pragma unroll
            for (int t = 0; t < 4; ++t)
                acc[ms][t] = __builtin_amdgcn_mfma_f32_16x16x32_bf16(
                    af, bf[t], acc[ms][t], 0, 0, 0);
        }
    }

    if (!GACC) {
        float pj[4][4];  // [ms][r]
#pragma unroll
        for (int a = 0; a < 4; ++a)
#pragma unroll
            for (int b = 0; b < 4; ++b) pj[a][b] = 0.f;
#pragma unroll
        for (int ms = 0; ms < 4; ++ms)
#pragma unroll
            for (int r = 0; r < 4; ++r) {
                const int j = j0 + ms * 16 + lg * 4 + r;
                const float* Bj = Bcol + (size_t)j * HID + w * 64 + lr;
#pragma unroll
                for (int t = 0; t < 4; ++t) {
                    float h = acc[ms][t][r] + as_t[t] + Bj[t * 16];
                    h = fmaxf(h, 0.01f * h);           // LeakyReLU
                    pj[ms][r] = fmaf(h, ws_t[t], pj[ms][r]);
                }
            }
#pragma unroll
        for (int ms = 0; ms < 4; ++ms)
#pragma unroll
            for (int r = 0; r < 4; ++r) {
                float v = pj[ms][r];
                v += __shfl_xor(v, 1);  v += __shfl_xor(v, 2);
                v += __shfl_xor(v, 4);  v += __shfl_xor(v, 8);
                if (lr == 0) red[w][ms * 16 + lg * 4 + r] = v;
            }
        __syncthreads();
        if (tid < 64)
            outp[(size_t)i * NN + j0 + tid] =
                red[0][tid] + red[1][tid] + red[2][tid] + red[3][tid];
    } else {
        float cf[4][4];
#pragma unroll
        for (int ms = 0; ms < 4; ++ms)
#pragma unroll
            for (int r = 0; r < 4; ++r) cf[ms][r] = conf_s[ms * 16 + lg * 4 + r];
        float gk[4] = {0.f, 0.f, 0.f, 0.f};
#pragma unroll
        for (int ms = 0; ms < 4; ++ms)
#pragma unroll
            for (int r = 0; r < 4; ++r) {
                const int j = j0 + ms * 16 + lg * 4 + r;
                const float* Bj = Bcol + (size_t)j * HID + w * 64 + lr;
#pragma unroll
                for (int t = 0; t < 4; ++t) {
                    float h = acc[ms][t][r] + as_t[t] + Bj[t * 16];
                    h = fmaxf(h, 0.f);
                    gk[t] = fmaf(cf[ms][r], h, gk[t]);
                }
            }
#pragma unroll
        for (int t = 0; t < 4; ++t) {
            float v = gk[t];
            v += __shfl_xor(v, 16);
            v += __shfl_xor(v, 32);
            if (lg == 0)
                atomicAdd(&outp[(size_t)i * DOUT + w * 64 + t * 16 + lr], v);
        }
    }
}

// ---------------------------------------------------------------- row softmax
__global__ __launch_bounds__(256) void k_softmax(
    const float* __restrict__ conf_raw, const float* __restrict__ mask,
    float* __restrict__ conf, float* __restrict__ s_out)
{
    const int i = blockIdx.x, tid = threadIdx.x;
    const int lane = tid & 63, w = tid >> 6;
    __shared__ float wred[3][4];

    const float r0 = conf_raw[(size_t)i * NN + tid];
    const float r1 = conf_raw[(size_t)i * NN + 256 + tid];
    const float mk0 = mask[(size_t)i * NN + tid];
    const float mk1 = mask[(size_t)i * NN + 256 + tid];

    float m = fmaxf(r0, r1);
#pragma unroll
    for (int off = 32; off; off >>= 1) m = fmaxf(m, __shfl_down(m, off));
    if (lane == 0) wred[0][w] = m;
    __syncthreads();
    const float M = fmaxf(fmaxf(wred[0][0], wred[0][1]), fmaxf(wred[0][2], wred[0][3]));

    const float e0 = __expf(r0 - M), e1 = __expf(r1 - M);
    float sa = e0 + e1;
    float sk = e0 * mk0 + e1 * mk1;
#pragma unroll
    for (int off = 32; off; off >>= 1) {
        sa += __shfl_down(sa, off);
        sk += __shfl_down(sk, off);
    }
    if (lane == 0) { wred[1][w] = sa; wred[2][w] = sk; }
    __syncthreads();
    const float SA = wred[1][0] + wred[1][1] + wred[1][2] + wred[1][3];
    const float SK = wred[2][0] + wred[2][1] + wred[2][2] + wred[2][3];
    const float dinv = 1.f / (SK + 1e-8f * SA);

    conf[(size_t)i * NN + tid]       = e0 * mk0 * dinv;
    conf[(size_t)i * NN + 256 + tid] = e1 * mk1 * dinv;
    if (tid == 0) s_out[i] = SK * dinv;
}

// ---------------------------------------------------------------- final small GEMM
__global__ __launch_bounds__(256) void k_out(
    const float* __restrict__ G, const float* __restrict__ cw2,
    const float* __restrict__ cb2, const float* __restrict__ s_in,
    float* __restrict__ out)
{
    const int i = blockIdx.x, o = threadIdx.x;
    __shared__ float Gs[DOUT];
    Gs[o] = G[(size_t)i * DOUT + o];
    __syncthreads();
    const float* wr = cw2 + (size_t)o * HID;
    float acc = 0.f;
#pragma unroll 4
    for (int k = 0; k < HID; ++k) acc = fmaf(Gs[k], wr[k], acc);
    out[(size_t)i * DOUT + o] = acc + s_in[i] * cb2[o];
}

// ---------------------------------------------------------------- launch
extern "C" void kernel_launch(void* const* d_in, const int* in_sizes, int n_in,
                              void* d_out, int out_size, void* d_ws, size_t ws_size,
                              hipStream_t stream)
{
    const float* obj  = (const float*)d_in[0];
    const float* bbox = (const float*)d_in[1];
    const float* mask = (const float*)d_in[2];
    const float* w1   = (const float*)d_in[3];
    const float* b1   = (const float*)d_in[4];
    const float* bn_g = (const float*)d_in[5];
    const float* bn_v = (const float*)d_in[8];
    const float* w2   = (const float*)d_in[9];
    const float* cw1  = (const float*)d_in[11];
    const float* cb1  = (const float*)d_in[12];
    const float* cw2  = (const float*)d_in[13];
    const float* cb2  = (const float*)d_in[14];

    float* ws   = (float*)d_ws;
    float* A    = ws + OFF_A;
    float* B    = ws + OFF_B;
    float* Ca   = ws + OFF_CA;
    float* Cb   = ws + OFF_CB;
    float* wsv  = ws + OFF_WSV;
    float* sbuf = ws + OFF_S;
    float* conf = ws + OFF_CONF;
    float* G    = ws + OFF_G;
    ushort* wswz = (ushort*)(ws + OFF_WSWZ);
    float* out  = (float*)d_out;

    k_pre_mfma<<<dim3(4, 8), 256, 0, stream>>>(obj, w1, cw1, b1, cb1, A, B, Ca, Cb);
    k_wsvec<<<1, 256, 0, stream>>>(w2, bn_g, bn_v, wsv);
    k_wprep<<<dim3(256, 2), 128, 0, stream>>>(w1, cw1, wswz);
    k_pair<0><<<dim3(8, NN), 256, 0, stream>>>(bbox, wswz, A, B, wsv, conf);
    k_softmax<<<NN, 256, 0, stream>>>(conf, mask, conf, sbuf);
    hipMemsetAsync(G, 0, (size_t)NN * DOUT * sizeof(float), stream);
    k_pair<1><<<dim3(8, NN), 256, 0, stream>>>(bbox, wswz + 32768, Ca, Cb, conf, G);
    k_out<<<NN, 256, 0, stream>>>(G, cw2, cb2, sbuf, out);
}